// Round 5
// baseline (1583.732 us; speedup 1.0000x reference)
//
#include <hip/hip_runtime.h>
#include <stdint.h>

#define VN   1000000
#define VDIM 256
#define GDIM 256
#define NH   16
#define NG   50000
#define HIDD 128
#define NTILES 15625   // VN / 64
#define TPB   5        // tiles per block; 15625 = 5 * 3125

using bf16x8 = __attribute__((ext_vector_type(8))) __bf16;
using f32x4  = __attribute__((ext_vector_type(4))) float;
using u16x4  = __attribute__((ext_vector_type(4))) unsigned short;
using u16x8  = __attribute__((ext_vector_type(8))) unsigned short;

__device__ __forceinline__ unsigned short f2bf(float f) {
  unsigned u = __float_as_uint(f);
  return (unsigned short)((u + 0x7FFFu + ((u >> 16) & 1u)) >> 16);  // RNE
}
__device__ __forceinline__ f32x4 fzero4() { f32x4 z = {0.f, 0.f, 0.f, 0.f}; return z; }

// ---------------- weight prep: fp32 -> bf16 in MFMA B-fragment order ----------------
// For W[K][N]: frag element idx = ((c*(K/32)+s)*64 + lane)*8 + j  holds W[32s+8*(lane>>4)+j][16c+(lane&15)]
__global__ void k_prep(const float* __restrict__ s1, const float* __restrict__ s2,
                       const float* __restrict__ t1, const float* __restrict__ t2,
                       unsigned short* __restrict__ WB) {
  int t = blockIdx.x * 256 + threadIdx.x;
  const float* W; unsigned short* dst; int K, N, lid;
  if (t < 32768)       { W = s1; dst = WB;          K = 256; N = 128; lid = t; }
  else if (t < 65536)  { W = t1; dst = WB + 32768;  K = 256; N = 128; lid = t - 32768; }
  else if (t < 98304)  { W = t2; dst = WB + 65536;  K = 128; N = 256; lid = t - 65536; }
  else if (t < 100352) { W = s2; dst = WB + 98304;  K = 128; N = 16;  lid = t - 98304; }
  else return;
  int j = lid & 7, l = (lid >> 3) & 63, rem = lid >> 9;
  int KS = K >> 5;
  int s = rem % KS, c = rem / KS;
  int row = 32 * s + 8 * (l >> 4) + j;
  int col = 16 * c + (l & 15);
  dst[lid] = f2bf(W[row * N + col]);
}

// ---------------- zero: out [NG*GDIM] + denom [NG*NH] ----------------
__global__ void k_zero(float* __restrict__ out, float* __restrict__ denom) {
  int i = blockIdx.x * 256 + threadIdx.x;
  float4 z = make_float4(0.f, 0.f, 0.f, 0.f);
  if (i < NG * GDIM / 4) ((float4*)out)[i] = z;
  int j = i - NG * GDIM / 4;
  if (j >= 0 && j < NG * NH / 4) ((float4*)denom)[j] = z;
}

// ---------------- fused main, software-pipelined over TPB tiles ----------------
// LDS (68 KB): Xs [0,32768); Hs [32768,49152); Ts [49152,65536); exs f32[64][16] [65536,69632)
// Pipeline per iter: [write Xs <- Xr] sync | B | sync | C1 C2 | sync | [issue Xr(t+1)] D E
// Drain-safety: no global load is CONSUMED between the Xr issue and the next iter's
// Xs-write, so no s_waitcnt forces the prefetch to retire early (vmcnt is in-order).
__global__ __launch_bounds__(256, 2) void k_main(
    const float* __restrict__ X,
    const unsigned short* __restrict__ WBs1,
    const unsigned short* __restrict__ WBt1,
    const unsigned short* __restrict__ WBs2,
    const unsigned short* __restrict__ WBt2,
    const int* __restrict__ seg,
    float* __restrict__ denom,
    float* __restrict__ out) {
  __shared__ __align__(16) char U[69632];
  char* const Xs = U;
  char* const Hs = U + 32768;
  char* const Ts = U + 49152;
  float* const exs = (float*)(U + 65536);

  const int tid  = threadIdx.x;
  const int lane = tid & 63;
  const int w    = tid >> 6;
  const int lg   = lane >> 4;
  const int t0   = blockIdx.x * TPB;

  // prologue: issue tile t0's X loads into registers
  float4 Xr[16];
  {
    const float4* Xg = (const float4*)(X + (size_t)t0 * 64 * VDIM);
    #pragma unroll
    for (int i = 0; i < 16; ++i) Xr[i] = Xg[tid + 256 * i];
  }

  for (int it = 0; it < TPB; ++it) {
    const int t = t0 + it;
    const size_t base = (size_t)t * 64;

    // ---- stage Xr -> Xs (bf16, 512B rows, swizzle byte^=((row&7)<<4))
    #pragma unroll
    for (int i = 0; i < 16; ++i) {
      int f = tid + 256 * i;
      int row = f >> 6, c4 = f & 63;
      u16x4 b = { f2bf(Xr[i].x), f2bf(Xr[i].y), f2bf(Xr[i].z), f2bf(Xr[i].w) };
      *(u16x4*)(Xs + row * 512 + ((c4 * 8) ^ ((row & 7) << 4))) = b;
    }
    // per-lane graph id for this tile (loaded EARLY: its consume-wait must not
    // land after the next Xr issue)
    const int gv = seg[base + lane];
    const int gp = __shfl_up(gv, 1, 64);
    const unsigned long long bmask = __ballot(gv != gp) | 1ull;
    __syncthreads();   // Xs ready

    // ---- Phase B: C1[64][256] = relu(X @ [Sw1|Tw1]); waves 0,1 -> Sw1, 2,3 -> Tw1
    {
      const unsigned short* WB = (w < 2) ? WBs1 : WBt1;
      const int cbase = (w & 1) * 4;
      f32x4 acc[4][4];
      #pragma unroll
      for (int r = 0; r < 4; ++r)
        #pragma unroll
        for (int c = 0; c < 4; ++c) acc[r][c] = fzero4();

      #pragma unroll
      for (int ks = 0; ks < 8; ++ks) {
        bf16x8 A[4];
        #pragma unroll
        for (int r = 0; r < 4; ++r) {
          int row = 16 * r + (lane & 15);
          int cb = 64 * ks + 16 * (lane >> 4);
          A[r] = *(const bf16x8*)(Xs + row * 512 + (cb ^ ((row & 7) << 4)));
        }
        #pragma unroll
        for (int ci = 0; ci < 4; ++ci) {
          bf16x8 B = *(const bf16x8*)(WB + (size_t)(((cbase + ci) * 8 + ks) * 64 + lane) * 8);
          #pragma unroll
          for (int r = 0; r < 4; ++r)
            acc[r][ci] = __builtin_amdgcn_mfma_f32_16x16x32_bf16(A[r], B, acc[r][ci], 0, 0, 0);
        }
      }

      // relu + bf16 -> Hs (waves 0,1) / Ts (waves 2,3), [64][128] 256B rows, swizzled
      char* const dst = (w < 2) ? Hs : Ts;
      #pragma unroll
      for (int ci = 0; ci < 4; ++ci) {
        int colf = cbase + ci;
        #pragma unroll
        for (int r = 0; r < 4; ++r) {
          #pragma unroll
          for (int j = 0; j < 4; ++j) {
            int row = 16 * r + 4 * (lane >> 4) + j;
            int col = 16 * colf + (lane & 15);
            float v = acc[r][ci][j];
            v = v > 0.f ? v : 0.f;
            *(unsigned short*)(dst + row * 256 + ((col * 2) ^ ((row & 7) << 4))) = f2bf(v);
          }
        }
      }
    }
    __syncthreads();   // Hs/Ts complete; Xs reads done

    // ---- Phase C1: scores = H1 @ Sw2 (wave w -> rows 16w..16w+15); ex -> exs + denom atomics
    {
      f32x4 sa = fzero4();
      #pragma unroll
      for (int ks = 0; ks < 4; ++ks) {
        int row = 16 * w + (lane & 15);
        int cb = 64 * ks + 16 * (lane >> 4);
        bf16x8 A2 = *(const bf16x8*)(Hs + row * 256 + (cb ^ ((row & 7) << 4)));
        bf16x8 B2 = *(const bf16x8*)(WBs2 + (size_t)(ks * 64 + lane) * 8);
        sa = __builtin_amdgcn_mfma_f32_16x16x32_bf16(A2, B2, sa, 0, 0, 0);
      }
      const int h = lane & 15;
      const int rowbase = 16 * w + 4 * lg;
      float ex[4]; int gs[4];
      #pragma unroll
      for (int j = 0; j < 4; ++j) {
        ex[j] = __expf(sa[j]);                       // |score| ~< 1.5: no max-subtract needed
        gs[j] = __shfl(gv, rowbase + j, 64);
        exs[(rowbase + j) * 16 + h] = ex[j];
      }
      float accd = ex[0]; int gcur = gs[0];
      #pragma unroll
      for (int j = 1; j < 4; ++j) {
        if (gs[j] == gcur) accd += ex[j];
        else { atomicAdd(denom + (size_t)gcur * NH + h, accd); gcur = gs[j]; accd = ex[j]; }
      }
      atomicAdd(denom + (size_t)gcur * NH + h, accd);
    }

    // ---- Phase C2: R = T1 @ Tw2 ; wave w -> col-frags 4w..4w+3
    f32x4 racc[4][4];
    #pragma unroll
    for (int r = 0; r < 4; ++r)
      #pragma unroll
      for (int c = 0; c < 4; ++c) racc[r][c] = fzero4();
    #pragma unroll
    for (int ks = 0; ks < 4; ++ks) {
      bf16x8 A[4];
      #pragma unroll
      for (int r = 0; r < 4; ++r) {
        int row = 16 * r + (lane & 15);
        int cbyte = 64 * ks + 16 * (lane >> 4);
        A[r] = *(const bf16x8*)(Ts + row * 256 + (cbyte ^ ((row & 7) << 4)));
      }
      #pragma unroll
      for (int ci = 0; ci < 4; ++ci) {
        bf16x8 B = *(const bf16x8*)(WBt2 + (size_t)(((4 * w + ci) * 4 + ks) * 64 + lane) * 8);
        #pragma unroll
        for (int r = 0; r < 4; ++r)
          racc[r][ci] = __builtin_amdgcn_mfma_f32_16x16x32_bf16(A[r], B, racc[r][ci], 0, 0, 0);
      }
    }
    __syncthreads();   // exs fully written by all waves

    // ---- issue next tile's X loads (nothing after this consumes a global load
    //      until the next iteration's Xs-write -> prefetch never force-drained)
    if (it + 1 < TPB) {
      const float4* Xg = (const float4*)(X + (size_t)(t + 1) * 64 * VDIM);
      #pragma unroll
      for (int i = 0; i < 16; ++i) Xr[i] = Xg[tid + 256 * i];
    }

    // ---- Phase D: racc = relu(racc) * ex[row][head]  (heads 4w..4w+3)
    #pragma unroll
    for (int r = 0; r < 4; ++r)
      #pragma unroll
      for (int j = 0; j < 4; ++j) {
        int row = 16 * r + 4 * lg + j;
        f32x4 wr = *(const f32x4*)(exs + row * 16 + 4 * w);
        #pragma unroll
        for (int ci = 0; ci < 4; ++ci) {
          float v = racc[r][ci][j];
          v = v > 0.f ? v : 0.f;
          racc[r][ci][j] = v * wr[ci];
        }
      }

    // ---- Phase E: in-register segmented column sums; interior -> store, edge -> atomic
    unsigned long long m = bmask;
    while (m) {
      int a = __builtin_ctzll(m);
      m &= m - 1;
      int b = m ? __builtin_ctzll(m) : 64;
      int g = __shfl(gv, a, 64);
      f32x4 s = fzero4();
      #pragma unroll
      for (int r = 0; r < 4; ++r)
        #pragma unroll
        for (int j = 0; j < 4; ++j) {
          int row = 16 * r + 4 * lg + j;
          float msk = ((unsigned)(row - a) < (unsigned)(b - a)) ? 1.f : 0.f;
          #pragma unroll
          for (int ci = 0; ci < 4; ++ci) s[ci] = fmaf(msk, racc[r][ci][j], s[ci]);
        }
      #pragma unroll
      for (int ci = 0; ci < 4; ++ci) {
        s[ci] += __shfl_xor(s[ci], 16, 64);
        s[ci] += __shfl_xor(s[ci], 32, 64);
      }
      bool edge = (a == 0) || (b == 64);
      if (lane < 16) {
        float* dst = out + (size_t)g * GDIM + 64 * w + lane;
        if (edge) {
          atomicAdd(dst,      s[0]); atomicAdd(dst + 16, s[1]);
          atomicAdd(dst + 32, s[2]); atomicAdd(dst + 48, s[3]);
        } else {
          dst[0] = s[0]; dst[16] = s[1]; dst[32] = s[2]; dst[48] = s[3];
        }
      }
    }
  }
}

// ---------------- epilogue: out[g][c] /= denom[g][c/16]; empty graphs -> 0 ----------------
__global__ void k_div(float* __restrict__ out, const float* __restrict__ denom) {
  int i = blockIdx.x * 256 + threadIdx.x;     // one float4 of out per thread
  if (i >= NG * GDIM / 4) return;
  float d = denom[(size_t)(i >> 6) * NH + ((i & 63) >> 2)];
  float r = d > 0.f ? 1.0f / d : 0.f;
  float4 v = ((float4*)out)[i];
  v.x *= r; v.y *= r; v.z *= r; v.w *= r;
  ((float4*)out)[i] = v;
}

extern "C" void kernel_launch(void* const* d_in, const int* in_sizes, int n_in,
                              void* d_out, int out_size, void* d_ws, size_t ws_size,
                              hipStream_t stream) {
  (void)in_sizes; (void)n_in; (void)out_size; (void)ws_size;
  const float* X  = (const float*)d_in[0];
  const int* seg  = (const int*)d_in[1];
  const float* s1 = (const float*)d_in[3];
  const float* s2 = (const float*)d_in[4];
  const float* t1 = (const float*)d_in[5];
  const float* t2 = (const float*)d_in[6];
  float* out = (float*)d_out;
  char* ws = (char*)d_ws;

  // ws layout: [0, 401408) weight frags bf16; [1<<19, +3.2MB) denom f32[NG][NH]
  unsigned short* WB = (unsigned short*)ws;
  float* denom = (float*)(ws + (1 << 19));

  k_prep<<<392, 256, 0, stream>>>(s1, s2, t1, t2, WB);
  k_zero<<<13282, 256, 0, stream>>>(out, denom);
  k_main<<<NTILES / TPB, 256, 0, stream>>>(X, WB, WB + 32768, WB + 98304, WB + 65536,
                                           seg, denom, out);
  k_div<<<12500, 256, 0, stream>>>(out, denom);
}

// Round 6
// 492.496 us; speedup vs baseline: 3.2157x; 3.2157x over previous
//
#include <hip/hip_runtime.h>
#include <stdint.h>

#define VN   1000000
#define VDIM 256
#define GDIM 256
#define NH   16
#define NG   50000
#define HIDD 128
#define NTILES 15625   // VN / 64

using bf16x8 = __attribute__((ext_vector_type(8))) __bf16;
using f32x4  = __attribute__((ext_vector_type(4))) float;
using u16x4  = __attribute__((ext_vector_type(4))) unsigned short;

__device__ __forceinline__ unsigned short f2bf(float f) {
  unsigned u = __float_as_uint(f);
  return (unsigned short)((u + 0x7FFFu + ((u >> 16) & 1u)) >> 16);  // RNE
}
__device__ __forceinline__ f32x4 fzero4() { f32x4 z = {0.f, 0.f, 0.f, 0.f}; return z; }

// ---------------- weight prep: fp32 -> bf16 in MFMA B-fragment order ----------------
// For W[K][N]: frag element idx = ((c*(K/32)+s)*64 + lane)*8 + j  holds W[32s+8*(lane>>4)+j][16c+(lane&15)]
__global__ void k_prep(const float* __restrict__ s1, const float* __restrict__ s2,
                       const float* __restrict__ t1, const float* __restrict__ t2,
                       unsigned short* __restrict__ WB) {
  int t = blockIdx.x * 256 + threadIdx.x;
  const float* W; unsigned short* dst; int K, N, lid;
  if (t < 32768)       { W = s1; dst = WB;          K = 256; N = 128; lid = t; }
  else if (t < 65536)  { W = t1; dst = WB + 32768;  K = 256; N = 128; lid = t - 32768; }
  else if (t < 98304)  { W = t2; dst = WB + 65536;  K = 128; N = 256; lid = t - 65536; }
  else if (t < 100352) { W = s2; dst = WB + 98304;  K = 128; N = 16;  lid = t - 98304; }
  else return;
  int j = lid & 7, l = (lid >> 3) & 63, rem = lid >> 9;
  int KS = K >> 5;
  int s = rem % KS, c = rem / KS;
  int row = 32 * s + 8 * (l >> 4) + j;
  int col = 16 * c + (l & 15);
  dst[lid] = f2bf(W[row * N + col]);
}

// ---------------- zero: out [NG*GDIM] + denom [NG*NH] ----------------
__global__ void k_zero(float* __restrict__ out, float* __restrict__ denom) {
  int i = blockIdx.x * 256 + threadIdx.x;
  float4 z = make_float4(0.f, 0.f, 0.f, 0.f);
  if (i < NG * GDIM / 4) ((float4*)out)[i] = z;
  int j = i - NG * GDIM / 4;
  if (j >= 0 && j < NG * NH / 4) ((float4*)denom)[j] = z;
}

// ---------------- fused main: one 64-row tile per block ----------------
// LDS (36 KB): U[0,32768) = Xs during {A,B}; after bar2 re-used as Hs [0,16384) + Ts [16384,32768)
//              exs f32[64][16] at [32768,36864)
// 36 KB -> 4 blocks/CU (16 waves/CU): X-load latency hidden by cross-block TLP, no reg prefetch.
__global__ __launch_bounds__(256, 4) void k_main(
    const float* __restrict__ X,
    const unsigned short* __restrict__ WBs1,
    const unsigned short* __restrict__ WBt1,
    const unsigned short* __restrict__ WBs2,
    const unsigned short* __restrict__ WBt2,
    const int* __restrict__ seg,
    float* __restrict__ denom,
    float* __restrict__ out) {
  __shared__ __align__(16) char U[36864];
  char* const Xs = U;
  char* const Hs = U;            // aliases Xs after bar2
  char* const Ts = U + 16384;
  float* const exs = (float*)(U + 32768);

  const int tid  = threadIdx.x;
  const int lane = tid & 63;
  const int w    = tid >> 6;
  const int lg   = lane >> 4;
  const size_t base = (size_t)blockIdx.x * 64;

  // per-lane graph id for the tile's 64 rows (lane <-> row)
  const int gv = seg[base + lane];
  const int gp = __shfl_up(gv, 1, 64);
  const unsigned long long bmask = __ballot(gv != gp) | 1ull;  // segment-start rows

  // ---- Phase A: stage X tile -> bf16 LDS, 512B rows, swizzle byte^=((row&7)<<4)
  {
    const float4* Xg = (const float4*)(X + base * VDIM);
    #pragma unroll
    for (int i = 0; i < 16; ++i) {
      int f = tid + 256 * i;
      int row = f >> 6, c4 = f & 63;
      float4 v = Xg[f];
      u16x4 b = { f2bf(v.x), f2bf(v.y), f2bf(v.z), f2bf(v.w) };
      *(u16x4*)(Xs + row * 512 + ((c4 * 8) ^ ((row & 7) << 4))) = b;
    }
  }
  __syncthreads();   // bar1: Xs ready

  // ---- Phase B: C1[64][256] = relu(X @ [Sw1|Tw1]); waves 0,1 -> Sw1, 2,3 -> Tw1
  {
    const unsigned short* WB = (w < 2) ? WBs1 : WBt1;
    const int cbase = (w & 1) * 4;
    f32x4 acc[4][4];
    #pragma unroll
    for (int r = 0; r < 4; ++r)
      #pragma unroll
      for (int c = 0; c < 4; ++c) acc[r][c] = fzero4();

    #pragma unroll
    for (int ks = 0; ks < 8; ++ks) {
      bf16x8 A[4];
      #pragma unroll
      for (int r = 0; r < 4; ++r) {
        int row = 16 * r + (lane & 15);
        int cb = 64 * ks + 16 * (lane >> 4);
        A[r] = *(const bf16x8*)(Xs + row * 512 + (cb ^ ((row & 7) << 4)));
      }
      #pragma unroll
      for (int ci = 0; ci < 4; ++ci) {
        bf16x8 B = *(const bf16x8*)(WB + (size_t)(((cbase + ci) * 8 + ks) * 64 + lane) * 8);
        #pragma unroll
        for (int r = 0; r < 4; ++r)
          acc[r][ci] = __builtin_amdgcn_mfma_f32_16x16x32_bf16(A[r], B, acc[r][ci], 0, 0, 0);
      }
    }
    __syncthreads();   // bar2: all Xs reads done; U becomes Hs/Ts

    // relu + bf16 -> Hs (waves 0,1) / Ts (waves 2,3), [64][128] 256B rows, swizzled
    char* const dst = (w < 2) ? Hs : Ts;
    #pragma unroll
    for (int ci = 0; ci < 4; ++ci) {
      int colf = cbase + ci;
      #pragma unroll
      for (int r = 0; r < 4; ++r) {
        #pragma unroll
        for (int j = 0; j < 4; ++j) {
          int row = 16 * r + 4 * (lane >> 4) + j;
          int col = 16 * colf + (lane & 15);
          float v = acc[r][ci][j];
          v = v > 0.f ? v : 0.f;
          *(unsigned short*)(dst + row * 256 + ((col * 2) ^ ((row & 7) << 4))) = f2bf(v);
        }
      }
    }
  }
  __syncthreads();   // bar3: Hs/Ts complete

  // ---- Phase C1: scores = H1 @ Sw2 (wave w -> rows 16w..16w+15); ex -> exs + denom atomics
  {
    f32x4 sa = fzero4();
    #pragma unroll
    for (int ks = 0; ks < 4; ++ks) {
      int row = 16 * w + (lane & 15);
      int cb = 64 * ks + 16 * (lane >> 4);
      bf16x8 A2 = *(const bf16x8*)(Hs + row * 256 + (cb ^ ((row & 7) << 4)));
      bf16x8 B2 = *(const bf16x8*)(WBs2 + (size_t)(ks * 64 + lane) * 8);
      sa = __builtin_amdgcn_mfma_f32_16x16x32_bf16(A2, B2, sa, 0, 0, 0);
    }
    const int h = lane & 15;
    const int rowbase = 16 * w + 4 * lg;
    float ex[4]; int gs[4];
    #pragma unroll
    for (int j = 0; j < 4; ++j) {
      ex[j] = __expf(sa[j]);                       // |score| ~< 1.5: no max-subtract needed
      gs[j] = __shfl(gv, rowbase + j, 64);
      exs[(rowbase + j) * 16 + h] = ex[j];
    }
    float accd = ex[0]; int gcur = gs[0];
    #pragma unroll
    for (int j = 1; j < 4; ++j) {
      if (gs[j] == gcur) accd += ex[j];
      else { atomicAdd(denom + (size_t)gcur * NH + h, accd); gcur = gs[j]; accd = ex[j]; }
    }
    atomicAdd(denom + (size_t)gcur * NH + h, accd);
  }

  // ---- Phase C2: R = T1 @ Tw2 ; wave w -> col-frags 4w..4w+3
  f32x4 racc[4][4];
  #pragma unroll
  for (int r = 0; r < 4; ++r)
    #pragma unroll
    for (int c = 0; c < 4; ++c) racc[r][c] = fzero4();
  #pragma unroll
  for (int ks = 0; ks < 4; ++ks) {
    bf16x8 A[4];
    #pragma unroll
    for (int r = 0; r < 4; ++r) {
      int row = 16 * r + (lane & 15);
      int cbyte = 64 * ks + 16 * (lane >> 4);
      A[r] = *(const bf16x8*)(Ts + row * 256 + (cbyte ^ ((row & 7) << 4)));
    }
    #pragma unroll
    for (int ci = 0; ci < 4; ++ci) {
      bf16x8 B = *(const bf16x8*)(WBt2 + (size_t)(((4 * w + ci) * 4 + ks) * 64 + lane) * 8);
      #pragma unroll
      for (int r = 0; r < 4; ++r)
        racc[r][ci] = __builtin_amdgcn_mfma_f32_16x16x32_bf16(A[r], B, racc[r][ci], 0, 0, 0);
    }
  }
  __syncthreads();   // bar4: exs fully written by all waves

  // ---- Phase D: racc = relu(racc) * ex[row][head]  (heads 4w..4w+3)
  #pragma unroll
  for (int r = 0; r < 4; ++r)
    #pragma unroll
    for (int j = 0; j < 4; ++j) {
      int row = 16 * r + 4 * lg + j;
      f32x4 wr = *(const f32x4*)(exs + row * 16 + 4 * w);
      #pragma unroll
      for (int ci = 0; ci < 4; ++ci) {
        float v = racc[r][ci][j];
        v = v > 0.f ? v : 0.f;
        racc[r][ci][j] = v * wr[ci];
      }
    }

  // ---- Phase E: in-register segmented column sums; interior -> store, edge -> atomic
  unsigned long long m = bmask;
  while (m) {
    int a = __builtin_ctzll(m);
    m &= m - 1;
    int b = m ? __builtin_ctzll(m) : 64;
    int g = __shfl(gv, a, 64);
    f32x4 s = fzero4();
    #pragma unroll
    for (int r = 0; r < 4; ++r)
      #pragma unroll
      for (int j = 0; j < 4; ++j) {
        int row = 16 * r + 4 * lg + j;
        float msk = ((unsigned)(row - a) < (unsigned)(b - a)) ? 1.f : 0.f;
        #pragma unroll
        for (int ci = 0; ci < 4; ++ci) s[ci] = fmaf(msk, racc[r][ci][j], s[ci]);
      }
    #pragma unroll
    for (int ci = 0; ci < 4; ++ci) {
      s[ci] += __shfl_xor(s[ci], 16, 64);
      s[ci] += __shfl_xor(s[ci], 32, 64);
    }
    bool edge = (a == 0) || (b == 64);
    if (lane < 16) {
      float* dst = out + (size_t)g * GDIM + 64 * w + lane;
      if (edge) {
        atomicAdd(dst,      s[0]); atomicAdd(dst + 16, s[1]);
        atomicAdd(dst + 32, s[2]); atomicAdd(dst + 48, s[3]);
      } else {
        dst[0] = s[0]; dst[16] = s[1]; dst[32] = s[2]; dst[48] = s[3];
      }
    }
  }
}

// ---------------- epilogue: out[g][c] /= denom[g][c/16]; empty graphs -> 0 ----------------
__global__ void k_div(float* __restrict__ out, const float* __restrict__ denom) {
  int i = blockIdx.x * 256 + threadIdx.x;     // one float4 of out per thread
  if (i >= NG * GDIM / 4) return;
  float d = denom[(size_t)(i >> 6) * NH + ((i & 63) >> 2)];
  float r = d > 0.f ? 1.0f / d : 0.f;
  float4 v = ((float4*)out)[i];
  v.x *= r; v.y *= r; v.z *= r; v.w *= r;
  ((float4*)out)[i] = v;
}

extern "C" void kernel_launch(void* const* d_in, const int* in_sizes, int n_in,
                              void* d_out, int out_size, void* d_ws, size_t ws_size,
                              hipStream_t stream) {
  (void)in_sizes; (void)n_in; (void)out_size; (void)ws_size;
  const float* X  = (const float*)d_in[0];
  const int* seg  = (const int*)d_in[1];
  const float* s1 = (const float*)d_in[3];
  const float* s2 = (const float*)d_in[4];
  const float* t1 = (const float*)d_in[5];
  const float* t2 = (const float*)d_in[6];
  float* out = (float*)d_out;
  char* ws = (char*)d_ws;

  // ws layout: [0, 401408) weight frags bf16; [1<<19, +3.2MB) denom f32[NG][NH]
  unsigned short* WB = (unsigned short*)ws;
  float* denom = (float*)(ws + (1 << 19));

  k_prep<<<392, 256, 0, stream>>>(s1, s2, t1, t2, WB);
  k_zero<<<13282, 256, 0, stream>>>(out, denom);
  k_main<<<NTILES, 256, 0, stream>>>(X, WB, WB + 32768, WB + 98304, WB + 65536,
                                     seg, denom, out);
  k_div<<<12500, 256, 0, stream>>>(out, denom);
}